// Round 4
// baseline (517.688 us; speedup 1.0000x reference)
//
#include <hip/hip_runtime.h>
#include <math.h>

#define C0f        299792458.0f
#define ALPHA_LINf 2.3025850929940458e-4f   // 1e-3 * ln(10)/10

#define NP   4          // num_pumps
#define MD   4          // modes
#define NC   100        // num_channels
#define NF   104        // NP + NC
#define FM   416        // NF * MD
#define NT   128        // 2 waves per block; threads 0..103 active
#define NR   4          // frequency rows per thread
#define RRSZ 801

// v + quad_perm<IMM>(v): DPP cross-lane add within each quad (VALU pipe, not LDS)
template <int IMM>
__device__ __forceinline__ float dpp_add(float v) {
    int r = __builtin_amdgcn_mov_dpp(__float_as_int(v), IMM, 0xF, 0xF, true);
    return v + __int_as_float(r);
}
#define QUAD_ALLRED(s) do { s = dpp_add<0xB1>(s); s = dpp_add<0x4E>(s); } while (0)

__global__ __launch_bounds__(NT, 1)   // 1 wave/EU floor -> VGPR cap 512, no spill
void raman_kernel(const float* __restrict__ x,
                  const float* __restrict__ sig_freq,
                  const float* __restrict__ sig_pow,
                  const float* __restrict__ sig_loss,
                  const float* __restrict__ loss_coef,
                  const float* __restrict__ overlap,
                  const float* __restrict__ raman,
                  const int*   __restrict__ steps_p,
                  const float* __restrict__ length_p,
                  const float* __restrict__ maxf_p,
                  float* __restrict__ out,
                  int L)
{
    __shared__ float rr[RRSZ + 1];                 // Raman LUT
    __shared__ float ff[NF];                       // frequencies
    __shared__ __align__(16) float Xb[2][FM];      // mode-interleaved state: Xb[buf][4*j+m]

    const int t = threadIdx.x;
    const int b = blockIdx.x;
    const int q = t & 3;                           // j-chunk AND owned mode
    const int u = t >> 2;                          // row-group index, active < 26
    const bool act = (u < 26);
    const int ua = act ? u : 25;

    // ---- stage LUT + frequency vector ----
    for (int k = t; k < L && k <= RRSZ; k += NT) rr[k] = raman[k];
    if (t < NF) ff[t] = (t < NP) ? (C0f / x[b * 20 + t]) : sig_freq[t - NP];
    __syncthreads();

    // ---- per-thread gain registers: 4 rows x 26-j chunk ----
    const float maxf  = maxf_p[0];
    const float scale = (float)(L - 1) / maxf;

    auto gain_of = [&](float fi, float fj) -> float {
        float fd  = fj - fi;                       // f_j - f_i
        float pos = fabsf(fd) * scale;
        int idx = (int)pos;                        // pos >= 0: trunc == floor
        if (idx > L - 2) idx = L - 2;
        float w  = pos - (float)idx;
        float gg = rr[idx] * (1.0f - w) + rr[idx + 1] * w;
        gg = (fd < 0.0f) ? -gg : gg;               // antisymmetric
        return gg * fmaxf(1.0f, fi / fj);          // photon-number scaling
    };

    float fr[NR];
#pragma unroll
    for (int r = 0; r < NR; ++r) fr[r] = ff[ua + 26 * r];

    float g[NR][26];
#pragma unroll
    for (int jj = 0; jj < 26; ++jj) {
        float fj = ff[26 * q + jj];
#pragma unroll
        for (int r = 0; r < NR; ++r) g[r][jj] = gain_of(fr[r], fj);
    }

    // overlap row for owned mode q
    const float Ox = overlap[q * MD + 0];
    const float Oy = overlap[q * MD + 1];
    const float Oz = overlap[q * MD + 2];
    const float Ow = overlap[q * MD + 3];

    // ---- per-thread state: elements e[r] = 4*(ua+26r)+q ----
    int   wofs[NR];
    float lossv[NR], P[NR];
#pragma unroll
    for (int r = 0; r < NR; ++r) {
        int row = ua + 26 * r;
        int e   = 4 * row + q;
        wofs[r] = e;
        if (r == 0 && ua < NP) {                   // pump element (rows 0..3)
            float wl = x[b * 20 + row] * 1e9f;
            lossv[r] = (loss_coef[2] + loss_coef[1] * wl
                        + loss_coef[0] * wl * wl) * ALPHA_LINf;
            P[r] = x[b * 20 + NP + e];
        } else {
            lossv[r] = sig_loss[e - NP * MD];
            P[r] = sig_pow[e - NP * MD];
        }
    }

    const int   nstep = steps_p[0] - 1;
    const float h  = length_p[0] / (float)(steps_p[0] - 1);
    const float hh = 0.5f * h;
    const float h6 = h / 6.0f;

    // one ODE eval: stage X (mode-interleaved), dot with g regs over chunk q,
    // DPP quad-allreduce over j-chunks, apply overlap row q.
    auto ode_eval = [&](const float Xs[NR], int buf, float k[NR]) {
        if (act) {
#pragma unroll
            for (int r = 0; r < NR; ++r) Xb[buf][wofs[r]] = Xs[r];
        }
        __syncthreads();
        const float* __restrict__ xr = &Xb[buf][104 * q];   // chunk q, 16B-aligned
        float s[NR][4];
#pragma unroll
        for (int r = 0; r < NR; ++r) { s[r][0] = 0.f; s[r][1] = 0.f; s[r][2] = 0.f; s[r][3] = 0.f; }
#pragma unroll
        for (int jj = 0; jj < 26; ++jj) {
            float4 xv = *(const float4*)(xr + 4 * jj);      // ds_read_b128
#pragma unroll
            for (int r = 0; r < NR; ++r) {
                float a = g[r][jj];
                s[r][0] += a * xv.x; s[r][1] += a * xv.y;
                s[r][2] += a * xv.z; s[r][3] += a * xv.w;
            }
        }
#pragma unroll
        for (int r = 0; r < NR; ++r) {
            QUAD_ALLRED(s[r][0]); QUAD_ALLRED(s[r][1]);
            QUAD_ALLRED(s[r][2]); QUAD_ALLRED(s[r][3]);
            float R = Ox * s[r][0] + Oy * s[r][1] + Oz * s[r][2] + Ow * s[r][3];
            k[r] = (R - lossv[r]) * Xs[r];
        }
    };

    for (int s = 0; s < nstep; ++s) {
        float k1[NR], k2[NR], k3[NR], k4[NR], Xt[NR];
        ode_eval(P, 0, k1);
#pragma unroll
        for (int r = 0; r < NR; ++r) Xt[r] = P[r] + hh * k1[r];
        ode_eval(Xt, 1, k2);
#pragma unroll
        for (int r = 0; r < NR; ++r) Xt[r] = P[r] + hh * k2[r];
        ode_eval(Xt, 0, k3);
#pragma unroll
        for (int r = 0; r < NR; ++r) Xt[r] = P[r] + h * k3[r];
        ode_eval(Xt, 1, k4);
#pragma unroll
        for (int r = 0; r < NR; ++r)
            P[r] += h6 * (k1[r] + 2.0f * k2[r] + 2.0f * k3[r] + k4[r]);
    }

    // ---- write signal spectrum (B, NC, MD): element e -> out idx e-16 ----
    if (act) {
#pragma unroll
        for (int r = 0; r < NR; ++r) {
            int e = wofs[r];
            if (e >= NP * MD) out[b * (NC * MD) + e - NP * MD] = P[r];
        }
    }
}

extern "C" void kernel_launch(void* const* d_in, const int* in_sizes, int n_in,
                              void* d_out, int out_size, void* d_ws, size_t ws_size,
                              hipStream_t stream) {
    const float* x   = (const float*)d_in[0];
    const float* sf  = (const float*)d_in[1];
    const float* sp  = (const float*)d_in[2];
    const float* sl  = (const float*)d_in[3];
    const float* lc  = (const float*)d_in[4];
    const float* ov  = (const float*)d_in[5];
    const float* rrp = (const float*)d_in[6];
    const int*   stp = (const int*)d_in[10];
    const float* len = (const float*)d_in[11];
    const float* mxf = (const float*)d_in[12];

    const int B = in_sizes[0] / (NP * (1 + MD));   // 512
    const int L = in_sizes[6];                     // 801

    raman_kernel<<<dim3(B), dim3(NT), 0, stream>>>(
        x, sf, sp, sl, lc, ov, rrp, stp, len, mxf, (float*)d_out, L);
}

// Round 5
// 306.314 us; speedup vs baseline: 1.6901x; 1.6901x over previous
//
#include <hip/hip_runtime.h>
#include <math.h>

#define C0f        299792458.0f
#define ALPHA_LINf 2.3025850929940458e-4f   // 1e-3 * ln(10)/10

#define NP   4
#define MD   4
#define NC   100
#define NF   104          // NP + NC
#define NT   256          // 4 waves; wave w owns M-tiles {w, w+4} (tile 7 dummy=0)
#define RRSZ 801
#define XROW 80           // dwords per packed-bf16 mode-row (160 bf16 slots >= 128 K-pad)

typedef __attribute__((ext_vector_type(8))) short short8;   // bf16 MFMA A/B frag (4 VGPR)
typedef __attribute__((ext_vector_type(4))) float float4v;  // MFMA C/D frag

// broadcast lane Q of each quad via DPP quad_perm (VALU pipe) — HW-verified rounds 2-4
template <int Q>
__device__ __forceinline__ float qbcast(float v) {
    int r = __builtin_amdgcn_mov_dpp(__float_as_int(v), Q * 0x55, 0xF, 0xF, true);
    return __int_as_float(r);
}

__global__ __launch_bounds__(NT, 2)   // 2 waves/EU -> VGPR cap 256
void raman_kernel(const float* __restrict__ x,
                  const float* __restrict__ sig_freq,
                  const float* __restrict__ sig_pow,
                  const float* __restrict__ sig_loss,
                  const float* __restrict__ loss_coef,
                  const float* __restrict__ overlap,
                  const float* __restrict__ raman,
                  const int*   __restrict__ steps_p,
                  const float* __restrict__ length_p,
                  const float* __restrict__ maxf_p,
                  float* __restrict__ out,
                  int L)
{
    __shared__ float rr[RRSZ + 1];                    // Raman LUT (setup only)
    __shared__ float ff[NF];                          // frequencies (setup only)
    __shared__ __align__(16) unsigned int Xp[2][MD * XROW];  // packed-bf16 state, dbuf

    const int t    = threadIdx.x;
    const int b    = blockIdx.x;
    const int lane = t & 63;
    const int w    = t >> 6;        // wave id 0..3
    const int g    = lane >> 4;     // lane-group 0..3
    const int c    = lane & 15;     // fragment col index (mode for c<4)
    const int mm   = lane & 3;

    // ---- stage LUT + frequency vector ----
    for (int k = t; k < L && k <= RRSZ; k += NT) rr[k] = raman[k];
    if (t < NF) ff[t] = (t < NP) ? (C0f / x[b * 20 + t]) : sig_freq[t - NP];
    __syncthreads();

    const float maxf  = maxf_p[0];
    const float scale = (float)(L - 1) / maxf;

    auto gain_of = [&](float fi, float fj) -> float {
        float fd  = fj - fi;                          // f_j - f_i
        float pos = fabsf(fd) * scale;
        int idx = (int)pos;                           // pos >= 0: trunc == floor
        if (idx > L - 2) idx = L - 2;
        float ww = pos - (float)idx;
        float gg = rr[idx] * (1.0f - ww) + rr[idx + 1] * ww;
        gg = (fd < 0.0f) ? -gg : gg;                  // antisymmetric
        return gg * fmaxf(1.0f, fi / fj);             // photon-number scaling
    };

    // ---- A fragments in registers: gain rows for tiles {w, w+4}, hi/lo bf16 split ----
    // A-frag layout: A[m = 16*T + (lane&15)][k = 32*kt + (lane>>4)*8 + jj]
    short8 Ahi[2][4], Alo[2][4];
#pragma unroll
    for (int tt = 0; tt < 2; ++tt) {
        const int Ti = w + 4 * tt;
        const int ia = 16 * Ti + c;
        const float fi = ff[(ia < NF) ? ia : 0];
#pragma unroll
        for (int kt = 0; kt < 4; ++kt) {
#pragma unroll
            for (int jj = 0; jj < 8; ++jj) {
                const int j = 32 * kt + 8 * g + jj;
                float gv = 0.0f;
                if (ia < NF && j < NF) gv = gain_of(fi, ff[j]);
                unsigned int gb = __float_as_uint(gv);
                float rem = gv - __uint_as_float(gb & 0xFFFF0000u);
                Ahi[tt][kt][jj] = (short)(gb >> 16);                      // RTZ hi
                Alo[tt][kt][jj] = (short)(__float_as_uint(rem) >> 16);    // RTZ lo
            }
        }
    }

    // overlap row for mode mm (symmetric matrix: row/col equivalent)
    const float Ox = overlap[mm * MD + 0];
    const float Oy = overlap[mm * MD + 1];
    const float Oz = overlap[mm * MD + 2];
    const float Ow = overlap[mm * MD + 3];

    // ---- state in C-layout regs: element (i = 16*T + 4*g + r, m = c), lanes c<4 ----
    float P[2][4], lossv[2][4];
#pragma unroll
    for (int tt = 0; tt < 2; ++tt) {
#pragma unroll
        for (int r = 0; r < 4; ++r) {
            const int i = 16 * (w + 4 * tt) + 4 * g + r;
            float Pv = 0.0f, lv = 0.0f;
            if (c < 4 && i < NF) {
                const int e = 4 * i + c;
                if (i < NP) {
                    float wl = x[b * 20 + i] * 1e9f;
                    lv = (loss_coef[2] + loss_coef[1] * wl
                          + loss_coef[0] * wl * wl) * ALPHA_LINf;
                    Pv = x[b * 20 + NP + e];
                } else {
                    lv = sig_loss[e - NP * MD];
                    Pv = sig_pow[e - NP * MD];
                }
            }
            P[tt][r] = Pv;
            lossv[tt][r] = lv;
        }
    }

    const int   nstep = steps_p[0] - 1;
    const float h  = length_p[0] / (float)(steps_p[0] - 1);
    const float hh = 0.5f * h;
    const float h6 = h / 6.0f;

    // one ODE eval: pack Xs->bf16 pairs->LDS (B-layout-friendly), barrier,
    // ds_read_b128 = B-frags, MFMA hi+lo, DPP quad overlap mix, k = (R-loss)*Xs
    auto ode_eval = [&](const float (&Xs)[2][4], int buf, float (&kk)[2][4]) {
        unsigned int* xb = &Xp[buf][0];
        if (c < 4) {
#pragma unroll
            for (int tt = 0; tt < 2; ++tt) {
                unsigned int d0 = (__float_as_uint(Xs[tt][0]) >> 16)
                                | (__float_as_uint(Xs[tt][1]) & 0xFFFF0000u);
                unsigned int d1 = (__float_as_uint(Xs[tt][2]) >> 16)
                                | (__float_as_uint(Xs[tt][3]) & 0xFFFF0000u);
                *(uint2*)(xb + c * XROW + 8 * (w + 4 * tt) + 2 * g) = make_uint2(d0, d1);
            }
        }
        __syncthreads();
        short8 B[4];
#pragma unroll
        for (int kt = 0; kt < 4; ++kt)
            B[kt] = *reinterpret_cast<const short8*>(xb + mm * XROW + 16 * kt + 4 * g);
#pragma unroll
        for (int tt = 0; tt < 2; ++tt) {
            float4v acc = {0.0f, 0.0f, 0.0f, 0.0f};
#pragma unroll
            for (int kt = 0; kt < 4; ++kt) {
                acc = __builtin_amdgcn_mfma_f32_16x16x32_bf16(Ahi[tt][kt], B[kt], acc, 0, 0, 0);
                acc = __builtin_amdgcn_mfma_f32_16x16x32_bf16(Alo[tt][kt], B[kt], acc, 0, 0, 0);
            }
#pragma unroll
            for (int r = 0; r < 4; ++r) {
                float v  = acc[r];                    // T[i][c] in C-layout
                float s0 = qbcast<0>(v);
                float s1 = qbcast<1>(v);
                float s2 = qbcast<2>(v);
                float s3 = qbcast<3>(v);
                float R  = Ox * s0 + Oy * s1 + Oz * s2 + Ow * s3;
                kk[tt][r] = (R - lossv[tt][r]) * Xs[tt][r];
            }
        }
    };

    for (int s = 0; s < nstep; ++s) {
        float k1[2][4], kc[2][4], Xs[2][4], ka[2][4];
        ode_eval(P, 0, k1);
#pragma unroll
        for (int tt = 0; tt < 2; ++tt)
#pragma unroll
            for (int r = 0; r < 4; ++r) { ka[tt][r] = k1[tt][r]; Xs[tt][r] = P[tt][r] + hh * k1[tt][r]; }
        ode_eval(Xs, 1, kc);
#pragma unroll
        for (int tt = 0; tt < 2; ++tt)
#pragma unroll
            for (int r = 0; r < 4; ++r) { ka[tt][r] += 2.0f * kc[tt][r]; Xs[tt][r] = P[tt][r] + hh * kc[tt][r]; }
        ode_eval(Xs, 0, kc);
#pragma unroll
        for (int tt = 0; tt < 2; ++tt)
#pragma unroll
            for (int r = 0; r < 4; ++r) { ka[tt][r] += 2.0f * kc[tt][r]; Xs[tt][r] = P[tt][r] + h * kc[tt][r]; }
        ode_eval(Xs, 1, kc);
#pragma unroll
        for (int tt = 0; tt < 2; ++tt)
#pragma unroll
            for (int r = 0; r < 4; ++r) P[tt][r] += h6 * (ka[tt][r] + kc[tt][r]);
    }

    // ---- write signal spectrum (B, NC, MD): element (i,m) -> out[4*i+m-16], i>=NP ----
#pragma unroll
    for (int tt = 0; tt < 2; ++tt) {
#pragma unroll
        for (int r = 0; r < 4; ++r) {
            const int i = 16 * (w + 4 * tt) + 4 * g + r;
            if (c < 4 && i >= NP && i < NF)
                out[b * (NC * MD) + 4 * i + c - NP * MD] = P[tt][r];
        }
    }
}

extern "C" void kernel_launch(void* const* d_in, const int* in_sizes, int n_in,
                              void* d_out, int out_size, void* d_ws, size_t ws_size,
                              hipStream_t stream) {
    const float* x   = (const float*)d_in[0];
    const float* sf  = (const float*)d_in[1];
    const float* sp  = (const float*)d_in[2];
    const float* sl  = (const float*)d_in[3];
    const float* lc  = (const float*)d_in[4];
    const float* ov  = (const float*)d_in[5];
    const float* rrp = (const float*)d_in[6];
    const int*   stp = (const int*)d_in[10];
    const float* len = (const float*)d_in[11];
    const float* mxf = (const float*)d_in[12];

    const int B = in_sizes[0] / (NP * (1 + MD));   // 512
    const int L = in_sizes[6];                     // 801

    raman_kernel<<<dim3(B), dim3(NT), 0, stream>>>(
        x, sf, sp, sl, lc, ov, rrp, stp, len, mxf, (float*)d_out, L);
}

// Round 6
// 264.964 us; speedup vs baseline: 1.9538x; 1.1561x over previous
//
#include <hip/hip_runtime.h>
#include <math.h>

#define C0f        299792458.0f
#define ALPHA_LINf 2.3025850929940458e-4f   // 1e-3 * ln(10)/10

#define NP   4
#define MD   4
#define NC   100
#define NF   104          // NP + NC
#define NT   256          // 4 waves; wave w owns M-tiles {w, w+4} (tile 7 dummy=0)
#define RRSZ 801
#define XROW 80           // dwords per packed-bf16 mode-row (160 bf16 slots >= 128 K-pad)

typedef __attribute__((ext_vector_type(8))) short short8;   // bf16 MFMA A/B frag (4 VGPR)
typedef __attribute__((ext_vector_type(4))) float float4v;  // MFMA C/D frag

// broadcast lane Q of each quad via DPP quad_perm (VALU pipe) — HW-verified rounds 2-5
template <int Q>
__device__ __forceinline__ float qbcast(float v) {
    int r = __builtin_amdgcn_mov_dpp(__float_as_int(v), Q * 0x55, 0xF, 0xF, true);
    return __int_as_float(r);
}

__global__ __launch_bounds__(NT, 2)   // 2 waves/EU -> VGPR cap 256
void raman_kernel(const float* __restrict__ x,
                  const float* __restrict__ sig_freq,
                  const float* __restrict__ sig_pow,
                  const float* __restrict__ sig_loss,
                  const float* __restrict__ loss_coef,
                  const float* __restrict__ overlap,
                  const float* __restrict__ raman,
                  const int*   __restrict__ steps_p,
                  const float* __restrict__ length_p,
                  const float* __restrict__ maxf_p,
                  float* __restrict__ out,
                  int L)
{
    __shared__ float rr[RRSZ + 1];                    // Raman LUT (setup only)
    __shared__ float ff[NF];                          // frequencies (setup only)
    __shared__ __align__(16) unsigned int Xp[2][MD * XROW];  // packed-bf16 state, dbuf

    const int t    = threadIdx.x;
    const int b    = blockIdx.x;
    const int lane = t & 63;
    const int w    = t >> 6;        // wave id 0..3
    const int g    = lane >> 4;     // lane-group 0..3
    const int c    = lane & 15;     // fragment col index (mode for c<4)
    const int mm   = lane & 3;

    // ---- stage LUT + frequency vector ----
    for (int k = t; k < L && k <= RRSZ; k += NT) rr[k] = raman[k];
    if (t < NF) ff[t] = (t < NP) ? (C0f / x[b * 20 + t]) : sig_freq[t - NP];
    __syncthreads();

    const float maxf  = maxf_p[0];
    const float scale = (float)(L - 1) / maxf;

    auto gain_of = [&](float fi, float fj) -> float {
        float fd  = fj - fi;                          // f_j - f_i
        float pos = fabsf(fd) * scale;
        int idx = (int)pos;                           // pos >= 0: trunc == floor
        if (idx > L - 2) idx = L - 2;
        float ww = pos - (float)idx;
        float gg = rr[idx] * (1.0f - ww) + rr[idx + 1] * ww;
        gg = (fd < 0.0f) ? -gg : gg;                  // antisymmetric
        return gg * fmaxf(1.0f, fi / fj);             // photon-number scaling
    };

    // ---- A fragments in registers: gain rows for tiles {w, w+4}, bf16 RTN-even ----
    // A-frag layout (HW-verified r5): A[m = 16*T + (lane&15)][k = 32*kt + (lane>>4)*8 + jj]
    short8 Ah[2][4];
#pragma unroll
    for (int tt = 0; tt < 2; ++tt) {
        const int Ti = w + 4 * tt;
        const int ia = 16 * Ti + c;
        const float fi = ff[(ia < NF) ? ia : 0];
#pragma unroll
        for (int kt = 0; kt < 4; ++kt) {
#pragma unroll
            for (int jj = 0; jj < 8; ++jj) {
                const int j = 32 * kt + 8 * g + jj;
                float gv = 0.0f;
                if (ia < NF && j < NF) gv = gain_of(fi, ff[j]);
                unsigned int gb = __float_as_uint(gv);
                unsigned int rb = (gb + 0x7FFFu + ((gb >> 16) & 1u)) >> 16;  // RTN-even
                Ah[tt][kt][jj] = (short)rb;
            }
        }
    }

    // overlap row for mode mm (symmetric matrix: row/col equivalent)
    const float Ox = overlap[mm * MD + 0];
    const float Oy = overlap[mm * MD + 1];
    const float Oz = overlap[mm * MD + 2];
    const float Ow = overlap[mm * MD + 3];

    // ---- state in C-layout regs: element (i = 16*T + 4*g + r, m = c), lanes c<4 ----
    float P[2][4], lossv[2][4];
#pragma unroll
    for (int tt = 0; tt < 2; ++tt) {
#pragma unroll
        for (int r = 0; r < 4; ++r) {
            const int i = 16 * (w + 4 * tt) + 4 * g + r;
            float Pv = 0.0f, lv = 0.0f;
            if (c < 4 && i < NF) {
                const int e = 4 * i + c;
                if (i < NP) {
                    float wl = x[b * 20 + i] * 1e9f;
                    lv = (loss_coef[2] + loss_coef[1] * wl
                          + loss_coef[0] * wl * wl) * ALPHA_LINf;
                    Pv = x[b * 20 + NP + e];
                } else {
                    lv = sig_loss[e - NP * MD];
                    Pv = sig_pow[e - NP * MD];
                }
            }
            P[tt][r] = Pv;
            lossv[tt][r] = lv;
        }
    }

    const int   nstep = steps_p[0] - 1;
    const float h  = length_p[0] / (float)(steps_p[0] - 1);
    const float hh = 0.5f * h;
    const float h6 = h / 6.0f;

    // one ODE eval: RTN-pack Xs->bf16 pairs->LDS, barrier, ds_read_b128 = B-frags,
    // 4 MFMA per tile, DPP quad overlap mix, k = (R-loss)*Xs
    auto ode_eval = [&](const float (&Xs)[2][4], int buf, float (&kk)[2][4]) {
        unsigned int* xb = &Xp[buf][0];
        if (c < 4) {
#pragma unroll
            for (int tt = 0; tt < 2; ++tt) {
                unsigned int r0 = __float_as_uint(Xs[tt][0]) + 0x8000u;  // round-half-up
                unsigned int r1 = __float_as_uint(Xs[tt][1]) + 0x8000u;
                unsigned int r2 = __float_as_uint(Xs[tt][2]) + 0x8000u;
                unsigned int r3 = __float_as_uint(Xs[tt][3]) + 0x8000u;
                unsigned int d0 = __builtin_amdgcn_perm(r1, r0, 0x07060302u); // {r1.hi, r0.hi}
                unsigned int d1 = __builtin_amdgcn_perm(r3, r2, 0x07060302u);
                *(uint2*)(xb + c * XROW + 8 * (w + 4 * tt) + 2 * g) = make_uint2(d0, d1);
            }
        }
        __syncthreads();
        short8 B[4];
#pragma unroll
        for (int kt = 0; kt < 4; ++kt)
            B[kt] = *reinterpret_cast<const short8*>(xb + mm * XROW + 16 * kt + 4 * g);
#pragma unroll
        for (int tt = 0; tt < 2; ++tt) {
            float4v acc = {0.0f, 0.0f, 0.0f, 0.0f};
#pragma unroll
            for (int kt = 0; kt < 4; ++kt)
                acc = __builtin_amdgcn_mfma_f32_16x16x32_bf16(Ah[tt][kt], B[kt], acc, 0, 0, 0);
#pragma unroll
            for (int r = 0; r < 4; ++r) {
                float v  = acc[r];                    // T[i][c] in C-layout
                float s0 = qbcast<0>(v);
                float s1 = qbcast<1>(v);
                float s2 = qbcast<2>(v);
                float s3 = qbcast<3>(v);
                float R  = Ox * s0 + Oy * s1 + Oz * s2 + Ow * s3;
                kk[tt][r] = (R - lossv[tt][r]) * Xs[tt][r];
            }
        }
    };

    for (int s = 0; s < nstep; ++s) {
        float k1[2][4], kc[2][4], Xs[2][4], ka[2][4];
        ode_eval(P, 0, k1);
#pragma unroll
        for (int tt = 0; tt < 2; ++tt)
#pragma unroll
            for (int r = 0; r < 4; ++r) { ka[tt][r] = k1[tt][r]; Xs[tt][r] = P[tt][r] + hh * k1[tt][r]; }
        ode_eval(Xs, 1, kc);
#pragma unroll
        for (int tt = 0; tt < 2; ++tt)
#pragma unroll
            for (int r = 0; r < 4; ++r) { ka[tt][r] += 2.0f * kc[tt][r]; Xs[tt][r] = P[tt][r] + hh * kc[tt][r]; }
        ode_eval(Xs, 0, kc);
#pragma unroll
        for (int tt = 0; tt < 2; ++tt)
#pragma unroll
            for (int r = 0; r < 4; ++r) { ka[tt][r] += 2.0f * kc[tt][r]; Xs[tt][r] = P[tt][r] + h * kc[tt][r]; }
        ode_eval(Xs, 1, kc);
#pragma unroll
        for (int tt = 0; tt < 2; ++tt)
#pragma unroll
            for (int r = 0; r < 4; ++r) P[tt][r] += h6 * (ka[tt][r] + kc[tt][r]);
    }

    // ---- write signal spectrum (B, NC, MD): element (i,m) -> out[4*i+m-16], i>=NP ----
#pragma unroll
    for (int tt = 0; tt < 2; ++tt) {
#pragma unroll
        for (int r = 0; r < 4; ++r) {
            const int i = 16 * (w + 4 * tt) + 4 * g + r;
            if (c < 4 && i >= NP && i < NF)
                out[b * (NC * MD) + 4 * i + c - NP * MD] = P[tt][r];
        }
    }
}

extern "C" void kernel_launch(void* const* d_in, const int* in_sizes, int n_in,
                              void* d_out, int out_size, void* d_ws, size_t ws_size,
                              hipStream_t stream) {
    const float* x   = (const float*)d_in[0];
    const float* sf  = (const float*)d_in[1];
    const float* sp  = (const float*)d_in[2];
    const float* sl  = (const float*)d_in[3];
    const float* lc  = (const float*)d_in[4];
    const float* ov  = (const float*)d_in[5];
    const float* rrp = (const float*)d_in[6];
    const int*   stp = (const int*)d_in[10];
    const float* len = (const float*)d_in[11];
    const float* mxf = (const float*)d_in[12];

    const int B = in_sizes[0] / (NP * (1 + MD));   // 512
    const int L = in_sizes[6];                     // 801

    raman_kernel<<<dim3(B), dim3(NT), 0, stream>>>(
        x, sf, sp, sl, lc, ov, rrp, stp, len, mxf, (float*)d_out, L);
}